// Round 1
// baseline (370.981 us; speedup 1.0000x reference)
//
#include <hip/hip_runtime.h>
#include <math.h>

// Problem constants (from reference)
//   N_MAX_L = [22,19,16,13], offsets [0,22,41,57], N_TOTAL=70
//   N_SPECIES=4, N_GRID=1024, R_CUT=5.0, HIDDEN=32, N_EDGES=400000
#define BLK 256

// LDS layout per species (floats):
//   W1[22][32] = 704 | W2[32][32] = 1024 | W3[32][32] = 1024 | W4[32][24] = 768
// species stride = 3524 floats (= 14096 B; 14096 mod 128 = 16 -> species bases
// staggered by 4 banks so per-lane species divergence doesn't collide banks)
#define SS 3524
#define W2_OFF 704
#define W3_OFF 1728
#define W4_OFF 2752

template <int L, int NL, int OFF>
__device__ __forceinline__ void rb_body(const float* __restrict__ r,
                                        const int* __restrict__ spc,
                                        const float* __restrict__ tbl,
                                        const float* __restrict__ W1,
                                        const float* __restrict__ W2,
                                        const float* __restrict__ W3,
                                        const float* __restrict__ W4,
                                        float* __restrict__ out, int nEdges,
                                        float* lds) {
  const int tid = threadIdx.x;

  // ---- stage weights for this L (all 4 species) into LDS ----
  for (int t = tid; t < 4 * 704; t += BLK) {
    int s = t / 704, rm = t - s * 704;
    lds[s * SS + rm] = W1[(L * 4 + s) * 704 + rm];
  }
  for (int t = tid; t < 4 * 1024; t += BLK) {
    int s = t >> 10, rm = t & 1023;
    lds[s * SS + W2_OFF + rm] = W2[(L * 4 + s) * 1024 + rm];
  }
  for (int t = tid; t < 4 * 1024; t += BLK) {
    int s = t >> 10, rm = t & 1023;
    lds[s * SS + W3_OFF + rm] = W3[(L * 4 + s) * 1024 + rm];
  }
  for (int t = tid; t < 4 * 704; t += BLK) {
    int s = t / 704, rm = t - s * 704;
    int hh = rm / 22, j = rm - hh * 22;  // pad rows 22 -> 24 for 16B alignment
    lds[s * SS + W4_OFF + hh * 24 + j] = W4[(L * 4 + s) * 704 + rm];
  }
  __syncthreads();

  const int e = blockIdx.x * BLK + tid;
  if (e >= nEdges) return;

  const float rr = r[e];
  const int s = spc[e];
  const float* Wl = lds + s * SS;

  // ---- spline eval (linear interp) ----
  // dx = R_CUT/(N_GRID-1) = 5/1023 ; xi = r/dx = r * 204.6
  float xi = rr * (1023.0f / 5.0f);
  int idx = (int)floorf(xi);
  idx = idx < 0 ? 0 : (idx > 1022 ? 1022 : idx);
  const float frac = xi - (float)idx;
  const float omf = 1.0f - frac;
  const float* t0 = tbl + idx * 70 + OFF;

  float x[NL];
#pragma unroll
  for (int k = 0; k < NL; k++) {
    x[k] = t0[k] * omf + t0[k + 70] * frac;
  }

  float h0[32], h1[32];

  // ---- layer 1: h0 = silu(x @ W1[:NL]) ----
#pragma unroll
  for (int j = 0; j < 32; j++) h0[j] = 0.0f;
#pragma unroll
  for (int k = 0; k < NL; k++) {
    const float xk = x[k];
#pragma unroll
    for (int j = 0; j < 32; j++) h0[j] += xk * Wl[k * 32 + j];
  }
#pragma unroll
  for (int j = 0; j < 32; j++) h0[j] = h0[j] / (1.0f + expf(-h0[j]));

  // ---- layer 2: h1 = silu(h0 @ W2) ----
#pragma unroll
  for (int j = 0; j < 32; j++) h1[j] = 0.0f;
#pragma unroll
  for (int k = 0; k < 32; k++) {
    const float hk = h0[k];
#pragma unroll
    for (int j = 0; j < 32; j++) h1[j] += hk * Wl[W2_OFF + k * 32 + j];
  }
#pragma unroll
  for (int j = 0; j < 32; j++) h1[j] = h1[j] / (1.0f + expf(-h1[j]));

  // ---- layer 3: h0 = silu(h1 @ W3) ----
#pragma unroll
  for (int j = 0; j < 32; j++) h0[j] = 0.0f;
#pragma unroll
  for (int k = 0; k < 32; k++) {
    const float hk = h1[k];
#pragma unroll
    for (int j = 0; j < 32; j++) h0[j] += hk * Wl[W3_OFF + k * 32 + j];
  }
#pragma unroll
  for (int j = 0; j < 32; j++) h0[j] = h0[j] / (1.0f + expf(-h0[j]));

  // ---- layer 4: y = h0 @ W4[:, :NL] ----
  float y[NL];
#pragma unroll
  for (int j = 0; j < NL; j++) y[j] = 0.0f;
#pragma unroll
  for (int k = 0; k < 32; k++) {
    const float hk = h0[k];
#pragma unroll
    for (int j = 0; j < NL; j++) y[j] += hk * Wl[W4_OFF + k * 24 + j];
  }

  float* o = out + (size_t)e * 70 + OFF;
#pragma unroll
  for (int j = 0; j < NL; j++) o[j] = y[j];
}

__global__ void __launch_bounds__(BLK) rb_all(const float* __restrict__ r,
                                              const int* __restrict__ spc,
                                              const float* __restrict__ tbl,
                                              const float* __restrict__ W1,
                                              const float* __restrict__ W2,
                                              const float* __restrict__ W3,
                                              const float* __restrict__ W4,
                                              float* __restrict__ out,
                                              int nEdges) {
  __shared__ float lds[4 * SS];
  switch (blockIdx.y) {
    case 0: rb_body<0, 22, 0>(r, spc, tbl, W1, W2, W3, W4, out, nEdges, lds); break;
    case 1: rb_body<1, 19, 22>(r, spc, tbl, W1, W2, W3, W4, out, nEdges, lds); break;
    case 2: rb_body<2, 16, 41>(r, spc, tbl, W1, W2, W3, W4, out, nEdges, lds); break;
    default: rb_body<3, 13, 57>(r, spc, tbl, W1, W2, W3, W4, out, nEdges, lds); break;
  }
}

extern "C" void kernel_launch(void* const* d_in, const int* in_sizes, int n_in,
                              void* d_out, int out_size, void* d_ws, size_t ws_size,
                              hipStream_t stream) {
  const float* r = (const float*)d_in[0];
  const int* spc = (const int*)d_in[1];
  const float* tbl = (const float*)d_in[2];
  const float* W1 = (const float*)d_in[3];
  const float* W2 = (const float*)d_in[4];
  const float* W3 = (const float*)d_in[5];
  const float* W4 = (const float*)d_in[6];
  float* out = (float*)d_out;
  const int n = in_sizes[0];

  dim3 grid((n + BLK - 1) / BLK, 4);
  hipLaunchKernelGGL(rb_all, grid, dim3(BLK), 0, stream, r, spc, tbl, W1, W2, W3,
                     W4, out, n);
}